// Round 9
// baseline (153.575 us; speedup 1.0000x reference)
//
#include <hip/hip_runtime.h>
#include <hip/hip_bf16.h>

#define B_DIM 8192
#define D_DIM 256
#define GRID_GEMM 1024
#define NCT 8    // 32-col tiles per block (256 cols per block)
#define NSUB 16  // staged 8KB sub-tiles per block (2 K-halves per col-tile)

constexpr float INV_T = 14.285714285714286f;   // 1/0.07; also the logsumexp shift M

typedef __bf16 bf16x8 __attribute__((ext_vector_type(8)));
typedef float  f32x16 __attribute__((ext_vector_type(16)));

#define GLOBAL_U32(p) ((const __attribute__((address_space(1))) unsigned int*)(p))
#define LDS_U32(p)    ((__attribute__((address_space(3))) unsigned int*)(p))

// s_waitcnt imm (gfx9): vm[3:0]=bits3:0, exp=bits6:4, lgkm=bits11:8, vm[5:4]=bits15:14
// vmcnt(4), expcnt/lgkmcnt = no-wait:
#define WAITCNT_VM4 0x0F74

__device__ inline unsigned short f2bf(float f) {
    union { float f; unsigned u; } x; x.f = f;
    unsigned r = x.u + 0x7fffu + ((x.u >> 16) & 1u);  // RNE
    return (unsigned short)(r >> 16);
}

// Kernel 1: q = normalize(h+r), t = normalize(t), BOTH stored in MFMA
// FRAGMENT order: 16B-slot ((row>>5)*16 + ks)*64 + hi*32 + (row&31) holds
// row's k = ks*16 + hi*8 + j (verified R5/R7/R8). Makes the GEMM's
// A-prologue and LDS staging/reads fully linear.
// Block 0 additionally zeroes rowsum/diagsum/ticket.
__global__ __launch_bounds__(256) void norm_kernel(
    const float* __restrict__ h, const float* __restrict__ r,
    const float* __restrict__ t,
    unsigned short* __restrict__ qws, unsigned short* __restrict__ tws,
    float* __restrict__ rowsum, float* __restrict__ diagsum, int* __restrict__ ticket)
{
    if (blockIdx.x == 0) {
        float4* rs4 = (float4*)rowsum;
#pragma unroll
        for (int i = 0; i < 8; ++i)
            rs4[threadIdx.x * 8 + i] = make_float4(0.f, 0.f, 0.f, 0.f);
        if (threadIdx.x == 0) { *diagsum = 0.f; *ticket = 0; }
    }

    const int wave = threadIdx.x >> 6;
    const int lane = threadIdx.x & 63;
    const int wg   = blockIdx.x * 4 + wave;      // 0..4095, 2 rows each

    // fragment store coords for this lane (k = 4*lane + j):
    const int ks  = lane >> 2;
    const int hi2 = (lane >> 1) & 1;
    const int sub = lane & 1;

#pragma unroll
    for (int i = 0; i < 2; ++i) {
        const int row = wg * 2 + i;              // 0..8191
        // ---- q = normalize(h+r) ----
        {
            float4 a = ((const float4*)h)[row * 64 + lane];
            float4 b = ((const float4*)r)[row * 64 + lane];
            float4 v = make_float4(a.x + b.x, a.y + b.y, a.z + b.z, a.w + b.w);
            float s = v.x * v.x + v.y * v.y + v.z * v.z + v.w * v.w;
#pragma unroll
            for (int off = 32; off; off >>= 1) s += __shfl_xor(s, off, 64);
            float scale = 1.0f / fmaxf(sqrtf(s), 1e-12f);
            ushort4 o;
            o.x = f2bf(v.x * scale); o.y = f2bf(v.y * scale);
            o.z = f2bf(v.z * scale); o.w = f2bf(v.w * scale);
            size_t slot16 = ((size_t)((row >> 5) * 16 + ks) * 64
                             + (size_t)(hi2 * 32 + (row & 31)));
            *(ushort4*)((unsigned char*)qws + slot16 * 16 + sub * 8) = o;
        }
        // ---- t = normalize(t) ----
        {
            float4 v = ((const float4*)t)[row * 64 + lane];
            float s = v.x * v.x + v.y * v.y + v.z * v.z + v.w * v.w;
#pragma unroll
            for (int off = 32; off; off >>= 1) s += __shfl_xor(s, off, 64);
            float scale = 1.0f / fmaxf(sqrtf(s), 1e-12f);
            ushort4 o;
            o.x = f2bf(v.x * scale); o.y = f2bf(v.y * scale);
            o.z = f2bf(v.z * scale); o.w = f2bf(v.w * scale);
            size_t slot16 = ((size_t)((row >> 5) * 16 + ks) * 64
                             + (size_t)(hi2 * 32 + (row & 31)));
            *(ushort4*)((unsigned char*)tws + slot16 * 16 + sub * 8) = o;
        }
    }
}

// Kernel 2: R8's verified pipeline with K-SPLIT staging: 8 KB sub-tiles
// (32 cols x K=128; contiguous in fragment order), ring 4 x 8 KB = 32 KB LDS
// -> 4 blocks/CU resident (was 2), grid 1024 = 32 rb x 32 cc. Same R0
// ordering (STAGE -> vmcnt -> barrier -> compute, prefetch distance 2,
// dummy tail) with vmcnt(4) (2 stages x 2 insts in flight). Accumulators
// persist across a col-tile's two sub-rounds; epilogue once per col-tile.
// __launch_bounds__ stays (256,2): (256,4) forced VGPR=64 and spilled (R6).
// VGPR 108 <= 128 permits the 4 waves/SIMD this grid now provides.
__global__ __launch_bounds__(256, 2) void gemm_lse_kernel(
    const unsigned char* __restrict__ qws, const unsigned char* __restrict__ tws,
    float* __restrict__ rowsum, float* __restrict__ diagsum,
    int* __restrict__ ticket, float* __restrict__ out)
{
    __shared__ __align__(16) unsigned char ldsB[4][8192];   // 32 KB ring
    __shared__ float wred[4];
    __shared__ int lastflag;

    const int tid  = threadIdx.x;
    const int lane = tid & 63;
    const int w    = tid >> 6;
    const int l31  = lane & 31;
    const int hi   = lane >> 5;

    const int cc   = blockIdx.x & 31;        // col chunk (fast -> XCD locality)
    const int rb   = blockIdx.x >> 5;        // row block 0..31
    const int row0 = rb * 256 + w * 64;      // this wave's 64 rows
    const int col0 = cc * 256;
    const int subt0 = cc * 16;               // first 8KB sub-tile of this chunk

    // stage 8KB sub-tile s (linear in fragment order) into ring buffer bufi
#define STAGE(s, bufi)                                                       \
    {                                                                        \
        const unsigned char* gs = tws + (size_t)(subt0 + (s)) * 8192;        \
        _Pragma("unroll")                                                    \
        for (int it = 0; it < 2; ++it)                                       \
            __builtin_amdgcn_global_load_lds(                                \
                GLOBAL_U32(gs + (it * 256 + tid) * 16),                      \
                LDS_U32(&ldsB[bufi][(it * 256 + tid) * 16]), 16, 0, 0);      \
    }

    // prologue: sub-tiles 0 and 1 in flight before the A-fragment loads
    STAGE(0, 0);
    STAGE(1, 1);

    // ---- A fragments in registers: rows row0..row0+63, full K=256 ----
    // frag-order qws: byte = row0*512 + rt*16384 + ks*1024 + lane*16
    // -> row = row0 + rt*32 + l31, k = ks*16 + hi*8 + j
    bf16x8 a[2][16];
    {
        const unsigned char* abase = qws + (size_t)row0 * 512 + lane * 16;
#pragma unroll
        for (int rt = 0; rt < 2; ++rt)
#pragma unroll
            for (int ks = 0; ks < 16; ++ks)
                a[rt][ks] = *(const bf16x8*)(abase + rt * 16384 + ks * 1024);
    }

    f32x16 rowacc[2] = {};
    float diagacc = 0.f;

    for (int ct = 0; ct < NCT; ++ct) {
        f32x16 acc0 = {}, acc1 = {};
#pragma unroll
        for (int kh = 0; kh < 2; ++kh) {
            const int s = ct * 2 + kh;
            // prefetch distance 2 (sub-tiles); tail: dummy re-stage of
            // sub-tile NSUB-1 into the dead target buffer keeps the
            // in-flight count uniform at 4.
            const int sn = (s + 2 < NSUB) ? s + 2 : NSUB - 1;
            STAGE(sn, (s + 2) & 3);

            // wait for sub-tile s only (s+1, s+2 = 4 insts stay in flight),
            // then a raw barrier -- NO vmcnt(0) drain.
            __builtin_amdgcn_s_waitcnt(WAITCNT_VM4);
            __builtin_amdgcn_s_barrier();

            const unsigned char* bbuf = ldsB[s & 3] + lane * 16;
#pragma unroll
            for (int ks = 0; ks < 8; ++ks) {
                bf16x8 b = *(const bf16x8*)(bbuf + ks * 1024);
                acc0 = __builtin_amdgcn_mfma_f32_32x32x16_bf16(
                           a[0][kh * 8 + ks], b, acc0, 0, 0, 0);
                acc1 = __builtin_amdgcn_mfma_f32_32x32x16_bf16(
                           a[1][kh * 8 + ks], b, acc1, 0, 0, 0);
            }
        }

        // epilogue once per col-tile: exp-sum
#pragma unroll
        for (int g = 0; g < 16; ++g) {
            rowacc[0][g] += __expf(fmaf(acc0[g], INV_T, -INV_T));
            rowacc[1][g] += __expf(fmaf(acc1[g], INV_T, -INV_T));
        }

        // diagonal tiles: wave-uniform condition, at most 2 of 8 col-tiles
        const int c0t = col0 + ct * 32;
        if (c0t == row0) {
#pragma unroll
            for (int g = 0; g < 16; ++g) {
                int rm = (g & 3) + 8 * (g >> 2) + 4 * hi;
                if (l31 == rm) diagacc += acc0[g] * INV_T;
            }
        }
        if (c0t == row0 + 32) {
#pragma unroll
            for (int g = 0; g < 16; ++g) {
                int rm = (g & 3) + 8 * (g >> 2) + 4 * hi;
                if (l31 == rm) diagacc += acc1[g] * INV_T;
            }
        }
    }

    // ---- once per block: reduce across the 32 column-lanes, then atomics ----
#pragma unroll
    for (int rt = 0; rt < 2; ++rt)
#pragma unroll
        for (int g = 0; g < 16; ++g) {
            float s = rowacc[rt][g];
            s += __shfl_xor(s, 1, 64);
            s += __shfl_xor(s, 2, 64);
            s += __shfl_xor(s, 4, 64);
            s += __shfl_xor(s, 8, 64);
            s += __shfl_xor(s, 16, 64);
            if (l31 == 0) {
                int grow = row0 + rt * 32 + (g & 3) + 8 * (g >> 2) + 4 * hi;
                atomicAdd(&rowsum[grow], s);
            }
        }

    float dsum = diagacc;
#pragma unroll
    for (int off = 32; off; off >>= 1) dsum += __shfl_xor(dsum, off, 64);
    if (lane == 0 && dsum != 0.f) atomicAdd(diagsum, dsum);

    // ---- ticket: last block computes the loss ----
    __syncthreads();
    if (tid == 0) {
        __threadfence();
        int old = __hip_atomic_fetch_add(ticket, 1, __ATOMIC_ACQ_REL,
                                         __HIP_MEMORY_SCOPE_AGENT);
        lastflag = (old == GRID_GEMM - 1);
    }
    __syncthreads();
    if (!lastflag) return;

    float lsum = 0.f;
    for (int rr = tid; rr < B_DIM; rr += 256) {
        float rs = __hip_atomic_load(&rowsum[rr], __ATOMIC_RELAXED,
                                     __HIP_MEMORY_SCOPE_AGENT);
        lsum += __logf(rs);
    }
#pragma unroll
    for (int off = 32; off; off >>= 1) lsum += __shfl_xor(lsum, off, 64);
    if (lane == 0) wred[w] = lsum;
    __syncthreads();
    if (tid == 0) {
        float ds = __hip_atomic_load(diagsum, __ATOMIC_RELAXED,
                                     __HIP_MEMORY_SCOPE_AGENT);
        float total = wred[0] + wred[1] + wred[2] + wred[3]
                    + (float)B_DIM * INV_T   // + M per row
                    - ds;                    // - positive logits
        out[0] = total / (float)B_DIM;
    }
}

extern "C" void kernel_launch(void* const* d_in, const int* in_sizes, int n_in,
                              void* d_out, int out_size, void* d_ws, size_t ws_size,
                              hipStream_t stream)
{
    const float* h = (const float*)d_in[0];
    const float* r = (const float*)d_in[1];
    const float* t = (const float*)d_in[2];

    unsigned char* ws = (unsigned char*)d_ws;
    unsigned short* qws = (unsigned short*)ws;                        // 4 MB (frag order)
    unsigned short* tws = (unsigned short*)(ws + 4u * 1024 * 1024);   // 4 MB (frag order)
    float* rowsum  = (float*)(ws + 8u * 1024 * 1024);                 // 32 KB
    float* diagsum = (float*)(ws + 8u * 1024 * 1024 + 32u * 1024);
    int*   ticket  = (int*)  (ws + 8u * 1024 * 1024 + 32u * 1024 + 16);

    norm_kernel<<<1024, 256, 0, stream>>>(h, r, t, qws, tws, rowsum, diagsum, ticket);
    gemm_lse_kernel<<<GRID_GEMM, 256, 0, stream>>>(
        (const unsigned char*)qws, (const unsigned char*)tws,
        rowsum, diagsum, ticket, (float*)d_out);
}